// Round 3
// baseline (649.447 us; speedup 1.0000x reference)
//
#include <hip/hip_runtime.h>
#include <stdint.h>

#define SEQ 2048
#define DHK 1024
#define DHV 1024
#define NB 8

typedef __attribute__((ext_vector_type(8))) short bf16x8;
typedef __attribute__((ext_vector_type(4))) float f32x4;

__device__ __forceinline__ unsigned short f2bf(float f) {
    uint32_t u = __builtin_bit_cast(uint32_t, f);
    u += 0x7fffu + ((u >> 16) & 1u);
    return (unsigned short)(u >> 16);
}

__device__ __forceinline__ float bf2f(unsigned short s) {
    return __builtin_bit_cast(float, (uint32_t)s << 16);
}

__device__ __forceinline__ void gload_lds16(const unsigned short* g, unsigned short* l) {
    __builtin_amdgcn_global_load_lds(
        (const __attribute__((address_space(1))) void*)g,
        (__attribute__((address_space(3))) void*)l,
        16, 0, 0);
}

// raw barrier: no implicit vmcnt(0) drain (unlike __syncthreads); memory clobber
// pins compiler ordering of ds/global ops across it.
#define WG_BARRIER() asm volatile("s_barrier" ::: "memory")

// ---- fused convert: q cvt + k transpose-cvt + v transpose-cvt, one launch ----
// blocks [0,4096): q elementwise; [4096,8192): k [B,1024,2048]->Kt [B,2048,1024];
// [8192,12288): v [B,2048,1024]->Vt [B,1024,2048]
__global__ __launch_bounds__(256) void fused_cvt(const float* __restrict__ q,
                                                 const float* __restrict__ k,
                                                 const float* __restrict__ v,
                                                 unsigned short* __restrict__ Qb,
                                                 unsigned short* __restrict__ Kt,
                                                 unsigned short* __restrict__ Vt) {
    __shared__ float tile[64][65];
    int bid = blockIdx.x;
    if (bid < 4096) {
        size_t i = ((size_t)bid * 256 + threadIdx.x) * 16;
#pragma unroll
        for (int c = 0; c < 4; ++c) {
            float4 x = *(const float4*)(q + i + c * 4);
            ushort4 o;
            o.x = f2bf(x.x); o.y = f2bf(x.y); o.z = f2bf(x.z); o.w = f2bf(x.w);
            *(ushort4*)(Qb + i + c * 4) = o;
        }
        return;  // q-blocks never reach the barrier (uniform per block)
    }
    const float* in;
    unsigned short* out;
    int R, C, b, x, y;
    if (bid < 8192) {
        int id = bid - 4096;
        b = id >> 9; int rem = id & 511;
        x = rem & 31; y = rem >> 5;           // x over C/64=32, y over R/64=16
        in = k; out = Kt; R = DHK; C = SEQ;
    } else {
        int id = bid - 8192;
        b = id >> 9; int rem = id & 511;
        x = rem & 15; y = rem >> 4;           // x over C/64=16, y over R/64=32
        in = v; out = Vt; R = SEQ; C = DHV;
    }
    int c0 = x * 64, r0 = y * 64;
    const float* ib = in + (size_t)b * R * C;
    unsigned short* ob = out + (size_t)b * R * C;
    int tr = threadIdx.x >> 4;
    int tc = (threadIdx.x & 15) * 4;
#pragma unroll
    for (int it = 0; it < 4; ++it) {
        int r = tr + it * 16;
        float4 w = *(const float4*)(ib + (size_t)(r0 + r) * C + c0 + tc);
        tile[r][tc + 0] = w.x; tile[r][tc + 1] = w.y;
        tile[r][tc + 2] = w.z; tile[r][tc + 3] = w.w;
    }
    __syncthreads();
#pragma unroll
    for (int it = 0; it < 4; ++it) {
        int c = tr + it * 16;
        ushort4 o;
        o.x = f2bf(tile[tc + 0][c]);
        o.y = f2bf(tile[tc + 1][c]);
        o.z = f2bf(tile[tc + 2][c]);
        o.w = f2bf(tile[tc + 3][c]);
        *(ushort4*)(ob + (size_t)(c0 + c) * R + r0 + tc) = o;
    }
}

// ------- 256x256 bf16 GEMM, BK=64, 8-phase counted-vmcnt schedule (T2+T3+T4+T5)
// 8 waves (2M x 4N), per-wave 128x64 output. 128 KiB LDS double-buffer.
// Half-tile order per K-tile: {B-h0, B-h1, A-ha, A-hb}; global stage stream
// ht = 0..TOTAL_HT-1, 7 prologue + 1/phase; vmcnt(6) at qd==3 keeps 3
// half-tiles in flight (WAR/readiness verified per-phase incl. rep boundary).
// MODE 0: E = exp(0.1 * Q@Kt^T) bf16. K=1024, N=2048. REPS=2: each block does
//   two adjacent N-tiles as one continuous stream (one prologue; epilogue-0
//   overlaps rep-1's in-flight staging). Grid 256 = 1 block/CU, one round.
// MODE 1: out = (E@Vt^T)/rowsum(E) fp32. K=2048, N=1024. rowsum via VALU over
//   af frags (off the MFMA pipe), realigned with shfl in the epilogue.
template <int MODE>
__global__ __launch_bounds__(512, 2) void attn_gemm8(const unsigned short* __restrict__ A,
                                                     const unsigned short* __restrict__ Bt,
                                                     void* __restrict__ Cout) {
    constexpr int K     = (MODE == 0) ? DHK : SEQ;
    constexpr int N     = (MODE == 0) ? SEQ : DHV;
    constexpr int REPS  = (MODE == 0) ? 2 : 1;
    constexpr int NKT   = K / 64;               // 16 / 32
    constexpr int LOGNKT = (MODE == 0) ? 4 : 5;
    constexpr int NITER = NKT / 2;              // 8 / 16
    constexpr int TOTAL_HT = REPS * NKT * 4;    // 128 both

    __shared__ __attribute__((aligned(16))) unsigned short As[2][256 * 64];
    __shared__ __attribute__((aligned(16))) unsigned short Bs[2][256 * 64];

    const int lid   = blockIdx.x;
    const int batch = lid & 7;          // XCD-partition: one batch per XCD
    const int t     = lid >> 3;         // [0,32)
    const int bm    = t >> 2;           // [0,8)
    const int bn    = t & 3;            // [0,4)

    const int tid  = threadIdx.x;
    const int wv   = tid >> 6;          // 0..7
    const int lane = tid & 63;
    const int wm   = wv & 1;            // row half (128 rows)
    const int wn   = wv >> 1;           // col quarter (64 cols)
    const int m16  = lane & 15;
    const int q    = lane >> 4;         // 0..3
    const int sw   = m16 & 7;
    const int lane_row = lane >> 3;     // 0..7
    const int g    = (lane & 7) ^ lane_row;  // swizzled k-chunk for staging

    const unsigned short* Ab = A  + (size_t)batch * SEQ * K;
    const unsigned short* Bb = Bt + (size_t)batch * N * K;
    const unsigned short* Ag = Ab + (size_t)(bm * 256 + lane_row) * K + g * 8;
    const unsigned short* Bg = Bb + (size_t)(bn * REPS * 256 + lane_row) * K + g * 8;

    // stage one 16KiB half-tile of the global stream: 512 threads x 2 x
    // global_load_lds(16B). LDS dest = wave-uniform base + lane*16B (linear);
    // global source carries the chunk swizzle (both-sides rule).
    auto stage = [&](int ht) {
        const int ktg = ht >> 2;
        const int sub = ht & 3;
        const int buf = ktg & 1;
        int ktl, rps;
        if constexpr (REPS > 1) { ktl = ktg & (NKT - 1); rps = ktg >> LOGNKT; }
        else                    { ktl = ktg; rps = 0; }
        const int k0 = ktl * 64;
        const size_t brep = (size_t)rps * 256 * K;
#pragma unroll
        for (int c = 0; c < 2; ++c) {
            const int lrow = wv * 16 + c * 8;          // 0..120, HT-local
            if (sub < 2) {
                const int rb = sub * 128 + lrow;       // B rows 0-255
                gload_lds16(Bg + brep + (size_t)rb * K + k0, &Bs[buf][rb * 64]);
            } else {
                // A-ha: [0-63]u[128-191]; A-hb: [64-127]u[192-255]
                const int rb = (sub == 2 ? 0 : 64) + lrow + (lrow & 64);
                gload_lds16(Ag + (size_t)rb * K + k0, &As[buf][rb * 64]);
            }
        }
    };

    f32x4 acc[8][4];
    float rs[8];  // MODE 1: per-slot rowsum partials; slot s covers rows s*16+m16
#pragma unroll
    for (int s = 0; s < 8; ++s) rs[s] = 0.0f;

    // prologue: half-tiles 0..6 (K-tile 0 complete + 3 of K-tile 1)
#pragma unroll
    for (int ht = 0; ht < 7; ++ht) stage(ht);
    asm volatile("s_waitcnt vmcnt(6)" ::: "memory");  // K-tile 0 landed
    WG_BARRIER();

    bf16x8 bfr[4][2];  // B-frags live across the 4 phases of a K-tile
#pragma unroll 1
    for (int rep = 0; rep < REPS; ++rep) {
#pragma unroll
        for (int i = 0; i < 8; ++i)
#pragma unroll
            for (int j = 0; j < 4; ++j)
#pragma unroll
                for (int e = 0; e < 4; ++e) acc[i][j][e] = 0.0f;

#pragma unroll 1
        for (int it = 0; it < NITER; ++it) {
            const bool last_it = (rep == REPS - 1) && (it == NITER - 1);
            const int ht_base = (rep * NITER + it) * 8 + 7;
#pragma unroll
            for (int p = 0; p < 8; ++p) {
                const int qd   = p & 3;
                const int rbuf = p >> 2;
                // --- ds-read register subtile (4 A-frags; +8 B-frags at qd==0) ---
                bf16x8 af[2][2];
#pragma unroll
                for (int i = 0; i < 2; ++i) {
                    const int mrow = wm * 128 + (qd * 2 + i) * 16 + m16;
#pragma unroll
                    for (int ss = 0; ss < 2; ++ss)
                        af[i][ss] = *(const bf16x8*)&As[rbuf][mrow * 64 + ((ss * 4 + q) ^ sw) * 8];
                }
                if (qd == 0) {
#pragma unroll
                    for (int nt = 0; nt < 4; ++nt) {
                        const int nrow = wn * 64 + nt * 16 + m16;
#pragma unroll
                        for (int ss = 0; ss < 2; ++ss)
                            bfr[nt][ss] = *(const bf16x8*)&Bs[rbuf][nrow * 64 + ((ss * 4 + q) ^ sw) * 8];
                    }
                }
                // --- stage next half-tile of the global stream ---
                {
                    const int ht = ht_base + p;
                    if (ht < TOTAL_HT) stage(ht);
                }
                WG_BARRIER();
                // compiler inserts the lgkmcnt wait before first MFMA use
                __builtin_amdgcn_s_setprio(1);
#pragma unroll
                for (int ss = 0; ss < 2; ++ss)
#pragma unroll
                    for (int i = 0; i < 2; ++i) {
                        const int mt = qd * 2 + i;
#pragma unroll
                        for (int nt = 0; nt < 4; ++nt)
                            acc[mt][nt] = __builtin_amdgcn_mfma_f32_16x16x32_bf16(
                                af[i][ss], bfr[nt][ss], acc[mt][nt], 0, 0, 0);
                    }
                __builtin_amdgcn_s_setprio(0);
                if (MODE == 1) {
                    // rowsum(E) partials on the VALU pipe (overlaps other waves'
                    // MFMA drain); exactly the staged bf16 values.
#pragma unroll
                    for (int i = 0; i < 2; ++i) {
                        float s0 = 0.0f;
#pragma unroll
                        for (int ss = 0; ss < 2; ++ss)
#pragma unroll
                            for (int e = 0; e < 8; ++e)
                                s0 += bf2f((unsigned short)af[i][ss][e]);
                        rs[qd * 2 + i] += s0;
                    }
                }
                if (qd == 3) {
                    if (!last_it) { asm volatile("s_waitcnt vmcnt(6)" ::: "memory"); }
                    else          { asm volatile("s_waitcnt vmcnt(0)" ::: "memory"); }
                }
                WG_BARRIER();
            }
        }

        // ---- per-rep epilogue (no LDS: safe against rep+1 stages in flight) ----
        // C/D layout: col = lane&15, row = (lane>>4)*4 + reg
        const int i0 = bm * 256 + wm * 128;
        const int t0 = (bn * REPS + rep) * 256 + wn * 64;
        if (MODE == 0) {
            unsigned short* E = (unsigned short*)Cout + (size_t)batch * SEQ * N;
#pragma unroll
            for (int mt = 0; mt < 8; ++mt)
#pragma unroll
                for (int e = 0; e < 4; ++e) {
                    int i = i0 + mt * 16 + q * 4 + e;
#pragma unroll
                    for (int nt = 0; nt < 4; ++nt) {
                        int cc = t0 + nt * 16 + m16;
                        E[(size_t)i * N + cc] = f2bf(__expf(0.1f * acc[mt][nt][e]));
                    }
                }
        } else {
            // q-reduce: each row's k-slices live across the 4 q-lane groups
#pragma unroll
            for (int s = 0; s < 8; ++s) {
                rs[s] += __shfl_xor(rs[s], 16);
                rs[s] += __shfl_xor(rs[s], 32);
            }
            float* O = (float*)Cout + (size_t)batch * SEQ * N;
#pragma unroll
            for (int mt = 0; mt < 8; ++mt)
#pragma unroll
                for (int e = 0; e < 4; ++e) {
                    int i = i0 + mt * 16 + q * 4 + e;
                    // row mt*16 + (q*4+e): reduced total lives in lane q*4+e (q=0 group)
                    float rsv = __shfl(rs[mt], q * 4 + e);
                    float inv = 1.0f / rsv;
#pragma unroll
                    for (int nt = 0; nt < 4; ++nt) {
                        int cc = t0 + nt * 16 + m16;
                        O[(size_t)i * N + cc] = acc[mt][nt][e] * inv;
                    }
                }
        }
    }
}

extern "C" void kernel_launch(void* const* d_in, const int* in_sizes, int n_in,
                              void* d_out, int out_size, void* d_ws, size_t ws_size,
                              hipStream_t stream) {
    (void)in_sizes; (void)n_in; (void)out_size; (void)ws_size;
    const float* q = (const float*)d_in[0];
    const float* k = (const float*)d_in[1];  // [B, D, S]
    const float* v = (const float*)d_in[2];  // [B, S, Dv]

    char* ws = (char*)d_ws;
    unsigned short* Qb = (unsigned short*)(ws);
    unsigned short* Kt = (unsigned short*)(ws + 33554432);   // bf16 [B, S, D]
    unsigned short* Vt = (unsigned short*)(ws + 67108864);   // bf16 [B, Dv, S]
    unsigned short* E  = (unsigned short*)(ws + 100663296);  // bf16 [B, S, S]

    fused_cvt<<<dim3(12288), dim3(256), 0, stream>>>(q, k, v, Qb, Kt, Vt);
    attn_gemm8<0><<<dim3(256), dim3(512), 0, stream>>>(Qb, Kt, (void*)E);
    attn_gemm8<1><<<dim3(256), dim3(512), 0, stream>>>(E, Vt, d_out);
}

// Round 4
// 368.247 us; speedup vs baseline: 1.7636x; 1.7636x over previous
//
#include <hip/hip_runtime.h>
#include <stdint.h>

#define SEQ 2048
#define DHK 1024
#define DHV 1024
#define NB 8

typedef __attribute__((ext_vector_type(8))) short bf16x8;
typedef __attribute__((ext_vector_type(4))) float f32x4;

__device__ __forceinline__ unsigned short f2bf(float f) {
    uint32_t u = __builtin_bit_cast(uint32_t, f);
    u += 0x7fffu + ((u >> 16) & 1u);
    return (unsigned short)(u >> 16);
}

__device__ __forceinline__ void gload_lds16(const unsigned short* g, unsigned short* l) {
    __builtin_amdgcn_global_load_lds(
        (const __attribute__((address_space(1))) void*)g,
        (__attribute__((address_space(3))) void*)l,
        16, 0, 0);
}

// raw barrier: no implicit vmcnt(0) drain (unlike __syncthreads); memory clobber
// pins compiler ordering of ds/global ops across it.
#define WG_BARRIER() asm volatile("s_barrier" ::: "memory")

// ---- fused convert: q cvt + k transpose-cvt + v transpose-cvt, one launch ----
// blocks [0,4096): q elementwise; [4096,8192): k [B,1024,2048]->Kt [B,2048,1024];
// [8192,12288): v [B,2048,1024]->Vt [B,1024,2048]
__global__ __launch_bounds__(256) void fused_cvt(const float* __restrict__ q,
                                                 const float* __restrict__ k,
                                                 const float* __restrict__ v,
                                                 unsigned short* __restrict__ Qb,
                                                 unsigned short* __restrict__ Kt,
                                                 unsigned short* __restrict__ Vt) {
    __shared__ float tile[64][65];
    int bid = blockIdx.x;
    if (bid < 4096) {
        size_t i = ((size_t)bid * 256 + threadIdx.x) * 16;
#pragma unroll
        for (int c = 0; c < 4; ++c) {
            float4 x = *(const float4*)(q + i + c * 4);
            ushort4 o;
            o.x = f2bf(x.x); o.y = f2bf(x.y); o.z = f2bf(x.z); o.w = f2bf(x.w);
            *(ushort4*)(Qb + i + c * 4) = o;
        }
        return;  // q-blocks never reach the barrier (uniform per block)
    }
    const float* in;
    unsigned short* out;
    int R, C, b, x, y;
    if (bid < 8192) {
        int id = bid - 4096;
        b = id >> 9; int rem = id & 511;
        x = rem & 31; y = rem >> 5;           // x over C/64=32, y over R/64=16
        in = k; out = Kt; R = DHK; C = SEQ;
    } else {
        int id = bid - 8192;
        b = id >> 9; int rem = id & 511;
        x = rem & 15; y = rem >> 4;           // x over C/64=16, y over R/64=32
        in = v; out = Vt; R = SEQ; C = DHV;
    }
    int c0 = x * 64, r0 = y * 64;
    const float* ib = in + (size_t)b * R * C;
    unsigned short* ob = out + (size_t)b * R * C;
    int tr = threadIdx.x >> 4;
    int tc = (threadIdx.x & 15) * 4;
#pragma unroll
    for (int it = 0; it < 4; ++it) {
        int r = tr + it * 16;
        float4 w = *(const float4*)(ib + (size_t)(r0 + r) * C + c0 + tc);
        tile[r][tc + 0] = w.x; tile[r][tc + 1] = w.y;
        tile[r][tc + 2] = w.z; tile[r][tc + 3] = w.w;
    }
    __syncthreads();
#pragma unroll
    for (int it = 0; it < 4; ++it) {
        int c = tr + it * 16;
        ushort4 o;
        o.x = f2bf(tile[tc + 0][c]);
        o.y = f2bf(tile[tc + 1][c]);
        o.z = f2bf(tile[tc + 2][c]);
        o.w = f2bf(tile[tc + 3][c]);
        *(ushort4*)(ob + (size_t)(c0 + c) * R + r0 + tc) = o;
    }
}

// ------- 256x256 bf16 GEMM, BK=64, 8-phase counted-vmcnt schedule (T2+T3+T4+T5)
// 8 waves (2M x 4N), per-wave 128x64 output. 128 KiB LDS double-buffer.
// Half-tile order per K-tile: {B-h0, B-h1, A-ha, A-hb}; 7 prologue + 1/phase;
// vmcnt(6) at qd==3 keeps 3 half-tiles in flight (WAR/readiness verified
// per-phase). One output tile per block (persistent REPS=2 measured -280us in
// R3: epilogue stores inside the counted-vmcnt stream wreck lockstep + L2).
// LDS swizzle: row r slot s holds global k-chunk s^(r&7) (conflict-free
// ds_read_b128; staged via pre-swizzled global source, linear LDS dest).
// MODE 0: E = exp(0.1 * Q@Kt^T) bf16.                     K=1024, N=2048
// MODE 1: out = (E@Vt^T)/rowsum(E) fp32; rowsum via ones-MFMA. K=2048, N=1024
template <int MODE>
__device__ __forceinline__ void attn_gemm8_body(const unsigned short* __restrict__ A,
                                                const unsigned short* __restrict__ Bt,
                                                void* __restrict__ Cout) {
    constexpr int K  = (MODE == 0) ? DHK : SEQ;
    constexpr int N  = (MODE == 0) ? SEQ : DHV;
    constexpr int TN = N / 256;                 // 8 / 4
    constexpr int NKT = K / 64;                 // 16 / 32
    constexpr int NITER = NKT / 2;              // 8 / 16

    __shared__ __attribute__((aligned(16))) unsigned short As[2][256 * 64];
    __shared__ __attribute__((aligned(16))) unsigned short Bs[2][256 * 64];

    const int lid   = blockIdx.x;
    const int batch = lid & 7;          // XCD-partition: one batch per XCD
    const int t     = lid >> 3;
    const int bm    = t / TN;
    const int bn    = t % TN;

    const int tid  = threadIdx.x;
    const int wv   = tid >> 6;          // 0..7
    const int lane = tid & 63;
    const int wm   = wv & 1;            // row half (128 rows)
    const int wn   = wv >> 1;           // col quarter (64 cols)
    const int m16  = lane & 15;
    const int q    = lane >> 4;         // 0..3
    const int sw   = m16 & 7;
    const int lane_row = lane >> 3;     // 0..7
    const int g    = (lane & 7) ^ lane_row;  // swizzled k-chunk for staging

    const unsigned short* Ab = A  + (size_t)batch * SEQ * K;
    const unsigned short* Bb = Bt + (size_t)batch * N * K;
    const unsigned short* Ag = Ab + (size_t)(bm * 256 + lane_row) * K + g * 8;
    const unsigned short* Bg = Bb + (size_t)(bn * 256 + lane_row) * K + g * 8;

    // stage one 16KiB half-tile: 512 threads x 2 x global_load_lds(16B).
    // LDS dest = wave-uniform base + lane*16B (linear); global source carries
    // the chunk swizzle (both-sides rule).
    auto stage = [&](int ktile, int sub) {
        const int buf = ktile & 1;
        const int k0  = ktile * 64;
#pragma unroll
        for (int c = 0; c < 2; ++c) {
            const int lrow = wv * 16 + c * 8;          // 0..120, HT-local
            if (sub < 2) {
                const int rb = sub * 128 + lrow;       // B rows 0-255
                gload_lds16(Bg + (size_t)rb * K + k0, &Bs[buf][rb * 64]);
            } else {
                // A-ha: [0-63]u[128-191]; A-hb: [64-127]u[192-255]
                const int rb = (sub == 2 ? 0 : 64) + lrow + (lrow & 64);
                gload_lds16(Ag + (size_t)rb * K + k0, &As[buf][rb * 64]);
            }
        }
    };

    f32x4 acc[8][4];
#pragma unroll
    for (int i = 0; i < 8; ++i)
#pragma unroll
        for (int j = 0; j < 4; ++j)
#pragma unroll
            for (int e = 0; e < 4; ++e) acc[i][j][e] = 0.0f;

    f32x4 acc1[8];  // MODE 1 only: rowsum(E) accumulator (E @ ones)
#pragma unroll
    for (int i = 0; i < 8; ++i)
#pragma unroll
        for (int e = 0; e < 4; ++e) acc1[i][e] = 0.0f;
    const short one_bf = (short)0x3F80;
    const bf16x8 ones = {one_bf, one_bf, one_bf, one_bf, one_bf, one_bf, one_bf, one_bf};

    // prologue: half-tiles 0..6 (K-tile 0 complete + 3 of K-tile 1)
#pragma unroll
    for (int ht = 0; ht < 7; ++ht) stage(ht >> 2, ht & 3);
    asm volatile("s_waitcnt vmcnt(6)" ::: "memory");  // K-tile 0 landed
    WG_BARRIER();

    bf16x8 bfr[4][2];  // B-frags live across the 4 phases of a K-tile
#pragma unroll 1
    for (int it = 0; it < NITER; ++it) {
        const bool notlast = (it + 1 < NITER);
#pragma unroll
        for (int p = 0; p < 8; ++p) {
            const int qd   = p & 3;
            const int rbuf = p >> 2;
            // --- ds-read register subtile (4 A-frags; +8 B-frags at qd==0) ---
            bf16x8 af[2][2];
#pragma unroll
            for (int i = 0; i < 2; ++i) {
                const int mrow = wm * 128 + (qd * 2 + i) * 16 + m16;
#pragma unroll
                for (int ss = 0; ss < 2; ++ss)
                    af[i][ss] = *(const bf16x8*)&As[rbuf][mrow * 64 + ((ss * 4 + q) ^ sw) * 8];
            }
            if (qd == 0) {
#pragma unroll
                for (int nt = 0; nt < 4; ++nt) {
                    const int nrow = wn * 64 + nt * 16 + m16;
#pragma unroll
                    for (int ss = 0; ss < 2; ++ss)
                        bfr[nt][ss] = *(const bf16x8*)&Bs[rbuf][nrow * 64 + ((ss * 4 + q) ^ sw) * 8];
                }
            }
            // --- stage next half-tile (counted, never drained in main loop) ---
            if (p == 0 || notlast) stage((7 + it * 8 + p) >> 2, (7 + p) & 3);
            WG_BARRIER();
            // compiler inserts the lgkmcnt wait before first MFMA use
            __builtin_amdgcn_s_setprio(1);
#pragma unroll
            for (int ss = 0; ss < 2; ++ss)
#pragma unroll
                for (int i = 0; i < 2; ++i) {
                    const int mt = qd * 2 + i;
#pragma unroll
                    for (int nt = 0; nt < 4; ++nt)
                        acc[mt][nt] = __builtin_amdgcn_mfma_f32_16x16x32_bf16(
                            af[i][ss], bfr[nt][ss], acc[mt][nt], 0, 0, 0);
                    if (MODE == 1)
                        acc1[mt] = __builtin_amdgcn_mfma_f32_16x16x32_bf16(
                            af[i][ss], ones, acc1[mt], 0, 0, 0);
                }
            __builtin_amdgcn_s_setprio(0);
            if (qd == 3) {
                if (notlast) { asm volatile("s_waitcnt vmcnt(6)" ::: "memory"); }
                else         { asm volatile("s_waitcnt vmcnt(0)" ::: "memory"); }
            }
            WG_BARRIER();
        }
    }

    // C/D layout: col = lane&15, row = (lane>>4)*4 + reg
    const int i0 = bm * 256 + wm * 128;
    const int t0 = bn * 256 + wn * 64;
    if (MODE == 0) {
        unsigned short* E = (unsigned short*)Cout + (size_t)batch * SEQ * N;
#pragma unroll
        for (int mt = 0; mt < 8; ++mt)
#pragma unroll
            for (int e = 0; e < 4; ++e) {
                int i = i0 + mt * 16 + q * 4 + e;
#pragma unroll
                for (int nt = 0; nt < 4; ++nt) {
                    int cc = t0 + nt * 16 + m16;
                    E[(size_t)i * N + cc] = f2bf(__expf(0.1f * acc[mt][nt][e]));
                }
            }
    } else {
        float* O = (float*)Cout + (size_t)batch * SEQ * N;
#pragma unroll
        for (int mt = 0; mt < 8; ++mt)
#pragma unroll
            for (int e = 0; e < 4; ++e) {
                int i = i0 + mt * 16 + q * 4 + e;
                float inv = 1.0f / acc1[mt][e];
#pragma unroll
                for (int nt = 0; nt < 4; ++nt) {
                    int cc = t0 + nt * 16 + m16;
                    O[(size_t)i * N + cc] = acc[mt][nt][e] * inv;
                }
            }
    }
}

// distinct names so rocprof rows disambiguate the two GEMMs
__global__ __launch_bounds__(512, 2) void attn_gemm8_qk(const unsigned short* __restrict__ A,
                                                        const unsigned short* __restrict__ Bt,
                                                        void* __restrict__ Cout) {
    attn_gemm8_body<0>(A, Bt, Cout);
}

__global__ __launch_bounds__(512, 2) void attn_gemm8_pv(const unsigned short* __restrict__ A,
                                                        const unsigned short* __restrict__ Bt,
                                                        void* __restrict__ Cout) {
    attn_gemm8_body<1>(A, Bt, Cout);
}

extern "C" void kernel_launch(void* const* d_in, const int* in_sizes, int n_in,
                              void* d_out, int out_size, void* d_ws, size_t ws_size,
                              hipStream_t stream) {
    (void)in_sizes; (void)n_in; (void)out_size; (void)ws_size;
    const float* q = (const float*)d_in[0];
    const float* k = (const float*)d_in[1];  // [B, D, S]
    const float* v = (const float*)d_in[2];  // [B, S, Dv]

    char* ws = (char*)d_ws;
    unsigned short* Qb = (unsigned short*)(ws);
    unsigned short* Kt = (unsigned short*)(ws + 33554432);   // bf16 [B, S, D]
    unsigned short* Vt = (unsigned short*)(ws + 67108864);   // bf16 [B, Dv, S]
    unsigned short* E  = (unsigned short*)(ws + 100663296);  // bf16 [B, S, S]

    fused_cvt<<<dim3(12288), dim3(256), 0, stream>>>(q, k, v, Qb, Kt, Vt);
    attn_gemm8_qk<<<dim3(NB * 8 * 8), dim3(512), 0, stream>>>(Qb, Kt, (void*)E);
    attn_gemm8_pv<<<dim3(NB * 8 * 4), dim3(512), 0, stream>>>(E, Vt, d_out);
}

// Round 5
// 364.516 us; speedup vs baseline: 1.7817x; 1.0102x over previous
//
#include <hip/hip_runtime.h>
#include <stdint.h>

#define SEQ 2048
#define DHK 1024
#define DHV 1024
#define NB 8

typedef __attribute__((ext_vector_type(8))) short bf16x8;
typedef __attribute__((ext_vector_type(4))) float f32x4;
typedef __attribute__((ext_vector_type(4))) uint32_t u32x4;

__device__ __forceinline__ unsigned short f2bf(float f) {
    uint32_t u = __builtin_bit_cast(uint32_t, f);
    u += 0x7fffu + ((u >> 16) & 1u);
    return (unsigned short)(u >> 16);
}

__device__ __forceinline__ uint32_t pack2(float a, float b) {
    return (uint32_t)f2bf(a) | ((uint32_t)f2bf(b) << 16);
}

__device__ __forceinline__ void gload_lds16(const unsigned short* g, unsigned short* l) {
    __builtin_amdgcn_global_load_lds(
        (const __attribute__((address_space(1))) void*)g,
        (__attribute__((address_space(3))) void*)l,
        16, 0, 0);
}

// raw barrier: no implicit vmcnt(0) drain (unlike __syncthreads); memory clobber
// pins compiler ordering of ds/global ops across it.
#define WG_BARRIER() asm volatile("s_barrier" ::: "memory")

// ---- fused convert: q cvt + k transpose-cvt + v transpose-cvt, one launch ----
// blocks [0,4096): q elementwise; [4096,8192): k [B,1024,2048]->Kt [B,2048,1024];
// [8192,12288): v [B,2048,1024]->Vt [B,1024,2048]
// v2: bf16-in-LDS transpose (half the LDS bytes of fp32), dword-pitch 33 =
// exact 2-way banks on both sides (free, m136); column-PAIR b32 reads so every
// global store is 16B. q path also 16B stores.
__global__ __launch_bounds__(256) void fused_cvt(const float* __restrict__ q,
                                                 const float* __restrict__ k,
                                                 const float* __restrict__ v,
                                                 unsigned short* __restrict__ Qb,
                                                 unsigned short* __restrict__ Kt,
                                                 unsigned short* __restrict__ Vt) {
    __shared__ uint32_t t32[64][33];   // 64 rows x 64 bf16 (32 dwords) + 1 pad dword
    int bid = blockIdx.x;
    if (bid < 4096) {
        size_t i = ((size_t)bid * 256 + threadIdx.x) * 16;
#pragma unroll
        for (int hh = 0; hh < 2; ++hh) {
            float4 a = *(const float4*)(q + i + hh * 8);
            float4 b = *(const float4*)(q + i + hh * 8 + 4);
            u32x4 o;
            o.x = pack2(a.x, a.y);
            o.y = pack2(a.z, a.w);
            o.z = pack2(b.x, b.y);
            o.w = pack2(b.z, b.w);
            *(u32x4*)(Qb + i + hh * 8) = o;
        }
        return;  // q-blocks never reach the barrier (uniform per block)
    }
    const float* in;
    unsigned short* out;
    int R, C, b, x, y;
    if (bid < 8192) {
        int id = bid - 4096;
        b = id >> 9; int rem = id & 511;
        x = rem & 31; y = rem >> 5;           // x over C/64=32, y over R/64=16
        in = k; out = Kt; R = DHK; C = SEQ;
    } else {
        int id = bid - 8192;
        b = id >> 9; int rem = id & 511;
        x = rem & 15; y = rem >> 4;           // x over C/64=16, y over R/64=32
        in = v; out = Vt; R = SEQ; C = DHV;
    }
    int c0 = x * 64, r0 = y * 64;
    const float* ib = in + (size_t)b * R * C;
    unsigned short* ob = out + (size_t)b * R * C;

    // phase A: coalesced fp32 row loads, convert, bf16 pair-writes to LDS.
    // banks: (r + 2m + u) mod 32 -> exact 2-way (free).
    int tr = threadIdx.x >> 4;      // 0..15
    int m  = threadIdx.x & 15;      // 0..15
#pragma unroll
    for (int it = 0; it < 4; ++it) {
        int r = tr + it * 16;
        float4 w = *(const float4*)(ib + (size_t)(r0 + r) * C + c0 + m * 4);
        t32[r][2 * m]     = pack2(w.x, w.y);
        t32[r][2 * m + 1] = pack2(w.z, w.w);
    }
    __syncthreads();

    // phase B: read column-PAIRS as b32 (banks (8seg+j+cpi) mod 32 -> 2-way),
    // assemble two ushort8 output rows, 16B stores (128B/row per wave).
    int cpi = threadIdx.x >> 3;     // 0..31 -> output rows 2*cpi, 2*cpi+1
    int seg = threadIdx.x & 7;      // 0..7  -> 16B segment within row
    uint32_t d[8];
#pragma unroll
    for (int j = 0; j < 8; ++j) d[j] = t32[seg * 8 + j][cpi];
    u32x4 lo, hi;
#pragma unroll
    for (int j = 0; j < 4; ++j) {
        lo[j] = (d[2 * j] & 0xFFFFu) | (d[2 * j + 1] << 16);
        hi[j] = (d[2 * j] >> 16) | (d[2 * j + 1] & 0xFFFF0000u);
    }
    int c2 = cpi * 2;
    *(u32x4*)(ob + (size_t)(c0 + c2) * R + r0 + seg * 8) = lo;
    *(u32x4*)(ob + (size_t)(c0 + c2 + 1) * R + r0 + seg * 8) = hi;
}

// ------- 256x256 bf16 GEMM, BK=64, 8-phase counted-vmcnt schedule (T2+T3+T4+T5)
// 8 waves (2M x 4N), per-wave 128x64 output. 128 KiB LDS double-buffer.
// Half-tile order per K-tile: {B-h0, B-h1, A-ha, A-hb}; 7 prologue + 1/phase;
// vmcnt(6) at qd==3 keeps 3 half-tiles in flight (WAR/readiness verified
// per-phase). One output tile per block (persistent REPS=2 measured -280us in
// R3: epilogue stores inside the counted-vmcnt stream wreck lockstep + L2).
// LDS swizzle: row r slot s holds global k-chunk s^(r&7) (conflict-free
// ds_read_b128; staged via pre-swizzled global source, linear LDS dest).
// MODE 0: E = exp(0.1 * Q@Kt^T) bf16.                     K=1024, N=2048
// MODE 1: out = (E@Vt^T)/rowsum(E) fp32; rowsum via ones-MFMA. K=2048, N=1024
template <int MODE>
__device__ __forceinline__ void attn_gemm8_body(const unsigned short* __restrict__ A,
                                                const unsigned short* __restrict__ Bt,
                                                void* __restrict__ Cout) {
    constexpr int K  = (MODE == 0) ? DHK : SEQ;
    constexpr int N  = (MODE == 0) ? SEQ : DHV;
    constexpr int TN = N / 256;                 // 8 / 4
    constexpr int NKT = K / 64;                 // 16 / 32
    constexpr int NITER = NKT / 2;              // 8 / 16

    __shared__ __attribute__((aligned(16))) unsigned short As[2][256 * 64];
    __shared__ __attribute__((aligned(16))) unsigned short Bs[2][256 * 64];

    const int lid   = blockIdx.x;
    const int batch = lid & 7;          // XCD-partition: one batch per XCD
    const int t     = lid >> 3;
    const int bm    = t / TN;
    const int bn    = t % TN;

    const int tid  = threadIdx.x;
    const int wv   = tid >> 6;          // 0..7
    const int lane = tid & 63;
    const int wm   = wv & 1;            // row half (128 rows)
    const int wn   = wv >> 1;           // col quarter (64 cols)
    const int m16  = lane & 15;
    const int q    = lane >> 4;         // 0..3
    const int sw   = m16 & 7;
    const int lane_row = lane >> 3;     // 0..7
    const int g    = (lane & 7) ^ lane_row;  // swizzled k-chunk for staging

    const unsigned short* Ab = A  + (size_t)batch * SEQ * K;
    const unsigned short* Bb = Bt + (size_t)batch * N * K;
    const unsigned short* Ag = Ab + (size_t)(bm * 256 + lane_row) * K + g * 8;
    const unsigned short* Bg = Bb + (size_t)(bn * 256 + lane_row) * K + g * 8;

    // stage one 16KiB half-tile: 512 threads x 2 x global_load_lds(16B).
    // LDS dest = wave-uniform base + lane*16B (linear); global source carries
    // the chunk swizzle (both-sides rule).
    auto stage = [&](int ktile, int sub) {
        const int buf = ktile & 1;
        const int k0  = ktile * 64;
#pragma unroll
        for (int c = 0; c < 2; ++c) {
            const int lrow = wv * 16 + c * 8;          // 0..120, HT-local
            if (sub < 2) {
                const int rb = sub * 128 + lrow;       // B rows 0-255
                gload_lds16(Bg + (size_t)rb * K + k0, &Bs[buf][rb * 64]);
            } else {
                // A-ha: [0-63]u[128-191]; A-hb: [64-127]u[192-255]
                const int rb = (sub == 2 ? 0 : 64) + lrow + (lrow & 64);
                gload_lds16(Ag + (size_t)rb * K + k0, &As[buf][rb * 64]);
            }
        }
    };

    f32x4 acc[8][4];
#pragma unroll
    for (int i = 0; i < 8; ++i)
#pragma unroll
        for (int j = 0; j < 4; ++j)
#pragma unroll
            for (int e = 0; e < 4; ++e) acc[i][j][e] = 0.0f;

    f32x4 acc1[8];  // MODE 1 only: rowsum(E) accumulator (E @ ones)
#pragma unroll
    for (int i = 0; i < 8; ++i)
#pragma unroll
        for (int e = 0; e < 4; ++e) acc1[i][e] = 0.0f;
    const short one_bf = (short)0x3F80;
    const bf16x8 ones = {one_bf, one_bf, one_bf, one_bf, one_bf, one_bf, one_bf, one_bf};

    // prologue: half-tiles 0..6 (K-tile 0 complete + 3 of K-tile 1)
#pragma unroll
    for (int ht = 0; ht < 7; ++ht) stage(ht >> 2, ht & 3);
    asm volatile("s_waitcnt vmcnt(6)" ::: "memory");  // K-tile 0 landed
    WG_BARRIER();

    bf16x8 bfr[4][2];  // B-frags live across the 4 phases of a K-tile
#pragma unroll 1
    for (int it = 0; it < NITER; ++it) {
        const bool notlast = (it + 1 < NITER);
#pragma unroll
        for (int p = 0; p < 8; ++p) {
            const int qd   = p & 3;
            const int rbuf = p >> 2;
            // --- ds-read register subtile (4 A-frags; +8 B-frags at qd==0) ---
            bf16x8 af[2][2];
#pragma unroll
            for (int i = 0; i < 2; ++i) {
                const int mrow = wm * 128 + (qd * 2 + i) * 16 + m16;
#pragma unroll
                for (int ss = 0; ss < 2; ++ss)
                    af[i][ss] = *(const bf16x8*)&As[rbuf][mrow * 64 + ((ss * 4 + q) ^ sw) * 8];
            }
            if (qd == 0) {
#pragma unroll
                for (int nt = 0; nt < 4; ++nt) {
                    const int nrow = wn * 64 + nt * 16 + m16;
#pragma unroll
                    for (int ss = 0; ss < 2; ++ss)
                        bfr[nt][ss] = *(const bf16x8*)&Bs[rbuf][nrow * 64 + ((ss * 4 + q) ^ sw) * 8];
                }
            }
            // --- stage next half-tile (counted, never drained in main loop) ---
            if (p == 0 || notlast) stage((7 + it * 8 + p) >> 2, (7 + p) & 3);
            WG_BARRIER();
            // compiler inserts the lgkmcnt wait before first MFMA use
            __builtin_amdgcn_s_setprio(1);
#pragma unroll
            for (int ss = 0; ss < 2; ++ss)
#pragma unroll
                for (int i = 0; i < 2; ++i) {
                    const int mt = qd * 2 + i;
#pragma unroll
                    for (int nt = 0; nt < 4; ++nt)
                        acc[mt][nt] = __builtin_amdgcn_mfma_f32_16x16x32_bf16(
                            af[i][ss], bfr[nt][ss], acc[mt][nt], 0, 0, 0);
                    if (MODE == 1)
                        acc1[mt] = __builtin_amdgcn_mfma_f32_16x16x32_bf16(
                            af[i][ss], ones, acc1[mt], 0, 0, 0);
                }
            __builtin_amdgcn_s_setprio(0);
            if (qd == 3) {
                if (notlast) { asm volatile("s_waitcnt vmcnt(6)" ::: "memory"); }
                else         { asm volatile("s_waitcnt vmcnt(0)" ::: "memory"); }
            }
            WG_BARRIER();
        }
    }

    // C/D layout: col = lane&15, row = (lane>>4)*4 + reg
    const int i0 = bm * 256 + wm * 128;
    const int t0 = bn * 256 + wn * 64;
    if (MODE == 0) {
        unsigned short* E = (unsigned short*)Cout + (size_t)batch * SEQ * N;
#pragma unroll
        for (int mt = 0; mt < 8; ++mt)
#pragma unroll
            for (int e = 0; e < 4; ++e) {
                int i = i0 + mt * 16 + q * 4 + e;
#pragma unroll
                for (int nt = 0; nt < 4; ++nt) {
                    int cc = t0 + nt * 16 + m16;
                    E[(size_t)i * N + cc] = f2bf(__expf(0.1f * acc[mt][nt][e]));
                }
            }
    } else {
        float* O = (float*)Cout + (size_t)batch * SEQ * N;
#pragma unroll
        for (int mt = 0; mt < 8; ++mt)
#pragma unroll
            for (int e = 0; e < 4; ++e) {
                int i = i0 + mt * 16 + q * 4 + e;
                float inv = 1.0f / acc1[mt][e];
#pragma unroll
                for (int nt = 0; nt < 4; ++nt) {
                    int cc = t0 + nt * 16 + m16;
                    O[(size_t)i * N + cc] = acc[mt][nt][e] * inv;
                }
            }
    }
}

// distinct names so rocprof rows disambiguate the two GEMMs
__global__ __launch_bounds__(512, 2) void attn_gemm8_qk(const unsigned short* __restrict__ A,
                                                        const unsigned short* __restrict__ Bt,
                                                        void* __restrict__ Cout) {
    attn_gemm8_body<0>(A, Bt, Cout);
}

__global__ __launch_bounds__(512, 2) void attn_gemm8_pv(const unsigned short* __restrict__ A,
                                                        const unsigned short* __restrict__ Bt,
                                                        void* __restrict__ Cout) {
    attn_gemm8_body<1>(A, Bt, Cout);
}

extern "C" void kernel_launch(void* const* d_in, const int* in_sizes, int n_in,
                              void* d_out, int out_size, void* d_ws, size_t ws_size,
                              hipStream_t stream) {
    (void)in_sizes; (void)n_in; (void)out_size; (void)ws_size;
    const float* q = (const float*)d_in[0];
    const float* k = (const float*)d_in[1];  // [B, D, S]
    const float* v = (const float*)d_in[2];  // [B, S, Dv]

    char* ws = (char*)d_ws;
    unsigned short* Qb = (unsigned short*)(ws);
    unsigned short* Kt = (unsigned short*)(ws + 33554432);   // bf16 [B, S, D]
    unsigned short* Vt = (unsigned short*)(ws + 67108864);   // bf16 [B, Dv, S]
    unsigned short* E  = (unsigned short*)(ws + 100663296);  // bf16 [B, S, S]

    fused_cvt<<<dim3(12288), dim3(256), 0, stream>>>(q, k, v, Qb, Kt, Vt);
    attn_gemm8_qk<<<dim3(NB * 8 * 8), dim3(512), 0, stream>>>(Qb, Kt, (void*)E);
    attn_gemm8_pv<<<dim3(NB * 8 * 4), dim3(512), 0, stream>>>(E, Vt, d_out);
}